// Round 4
// baseline (4866.003 us; speedup 1.0000x reference)
//
#include <hip/hip_runtime.h>

#define DD    512
#define SS    2048
#define NB    4
#define TOK   8192          // NB*SS
#define SEQM  4100
#define NACT  8
#define NBEAM 10
#define LNEPS 1e-5f

// monotone mapping float -> uint (order-preserving for all finite floats)
__device__ __forceinline__ unsigned fmono(float f) {
  unsigned u = __float_as_uint(f);
  return (u & 0x80000000u) ? ~u : (u | 0x80000000u);
}

// ---------------------------------------------------------------------------
// G1: ct[b, s, d] = relu( sum_t x[b,d,t] * tril(weight0)[t,s] )
// A = x [m=(b,d)][k=t] lda=2048, B = weight [k][n=s] ldb=4100 masked k>=n.
// Output written transposed into ct [B][S][D]. Triangular: k starts at n0.
// ---------------------------------------------------------------------------
__global__ __launch_bounds__(256) void k_gemm_tril(
    const float* __restrict__ X, const float* __restrict__ W,
    float* __restrict__ Ct)
{
  __shared__ float As[16][132];
  __shared__ float Bs[16][132];
  const int tid = threadIdx.x;
  const int m0 = blockIdx.x * 128;
  const int n0 = blockIdx.y * 128;
  const int tm = tid >> 4, tn = tid & 15;
  float acc[8][8];
#pragma unroll
  for (int i = 0; i < 8; i++)
#pragma unroll
    for (int j = 0; j < 8; j++) acc[i][j] = 0.f;

  for (int k0 = n0; k0 < SS; k0 += 16) {
#pragma unroll
    for (int i = 0; i < 2; i++) {
      int id = tid + 256 * i;
      int r = id >> 2;
      int c4 = (id & 3) << 2;
      float4 av = *(const float4*)(X + (size_t)(m0 + r) * SS + k0 + c4);
      As[c4 + 0][r] = av.x; As[c4 + 1][r] = av.y;
      As[c4 + 2][r] = av.z; As[c4 + 3][r] = av.w;
    }
#pragma unroll
    for (int i = 0; i < 2; i++) {
      int id = tid + 256 * i;
      int r = id >> 5;
      int c = (id & 31) << 2;
      int kg = k0 + r;
      float4 bv = *(const float4*)(W + (size_t)kg * SEQM + n0 + c);
      int nc = n0 + c;
      bv.x = (kg >= nc + 0) ? bv.x : 0.f;
      bv.y = (kg >= nc + 1) ? bv.y : 0.f;
      bv.z = (kg >= nc + 2) ? bv.z : 0.f;
      bv.w = (kg >= nc + 3) ? bv.w : 0.f;
      *(float4*)&Bs[r][c] = bv;
    }
    __syncthreads();
#pragma unroll
    for (int kk = 0; kk < 16; kk++) {
      float4 a0 = *(const float4*)&As[kk][tm * 8];
      float4 a1 = *(const float4*)&As[kk][tm * 8 + 4];
      float4 b0 = *(const float4*)&Bs[kk][tn * 8];
      float4 b1 = *(const float4*)&Bs[kk][tn * 8 + 4];
      float a[8] = {a0.x, a0.y, a0.z, a0.w, a1.x, a1.y, a1.z, a1.w};
      float b[8] = {b0.x, b0.y, b0.z, b0.w, b1.x, b1.y, b1.z, b1.w};
#pragma unroll
      for (int i = 0; i < 8; i++)
#pragma unroll
        for (int j = 0; j < 8; j++) acc[i][j] = fmaf(a[i], b[j], acc[i][j]);
    }
    __syncthreads();
  }
  const int bI = m0 >> 9;               // batch (128-tile stays inside one b)
  const int d0 = (m0 & 511) + tm * 8;
#pragma unroll
  for (int j = 0; j < 8; j++) {
    int s = n0 + tn * 8 + j;
    float4 v0, v1;
    v0.x = fmaxf(acc[0][j], 0.f); v0.y = fmaxf(acc[1][j], 0.f);
    v0.z = fmaxf(acc[2][j], 0.f); v0.w = fmaxf(acc[3][j], 0.f);
    v1.x = fmaxf(acc[4][j], 0.f); v1.y = fmaxf(acc[5][j], 0.f);
    v1.z = fmaxf(acc[6][j], 0.f); v1.w = fmaxf(acc[7][j], 0.f);
    float* dst = Ct + ((size_t)bI * SS + s) * DD + d0;
    *(float4*)dst = v0;
    *(float4*)(dst + 4) = v1;
  }
}

// ---------------------------------------------------------------------------
// Generic [M,512] @ [512,512] GEMM (ldb=512), with strided A-row layout:
// compact row gm maps to A-row (gm/rowsPerTok)*strideTok + gm%rowsPerTok.
// (identity when rowsPerTok==strideTok; used for the [token][10][D] states
// buffer whose fixed stride prevents the turn-1 cross-token race)
// mode 0: + biasVec, no relu      (MLP output layers, gpre)
// mode 1: + biasVec, relu         (MLP hidden layers)
// mode 2: + gpre[gm/rowsPerTok][:], relu   (beam gna layer 1)
// C written compact by gm. All pointer args must be valid (never null).
// ---------------------------------------------------------------------------
__global__ __launch_bounds__(256) void k_gemm512(
    const float* __restrict__ A, const float* __restrict__ W,
    const float* __restrict__ biasVec, const float* __restrict__ gpre,
    int rowsPerTok, int strideTok, float* __restrict__ C, int mode)
{
  __shared__ float As[16][132];
  __shared__ float Bs[16][132];
  const int tid = threadIdx.x;
  const int m0 = blockIdx.x * 128;
  const int n0 = blockIdx.y * 128;
  const int tm = tid >> 4, tn = tid & 15;

  // Hoisted A-row remap for this thread's two staging rows.
  const int c4 = (tid & 3) << 2;
  const int r0 = tid >> 2;            // 0..63
  const int r1 = r0 + 64;             // 64..127
  const int gm0 = m0 + r0, gm1 = m0 + r1;
  const int t0i = gm0 / rowsPerTok, t1i = gm1 / rowsPerTok;
  const float* arow0 =
      A + ((size_t)t0i * strideTok + (gm0 - t0i * rowsPerTok)) * DD;
  const float* arow1 =
      A + ((size_t)t1i * strideTok + (gm1 - t1i * rowsPerTok)) * DD;

  float acc[8][8];
#pragma unroll
  for (int i = 0; i < 8; i++)
#pragma unroll
    for (int j = 0; j < 8; j++) acc[i][j] = 0.f;

  for (int k0 = 0; k0 < DD; k0 += 16) {
    {
      float4 av = *(const float4*)(arow0 + k0 + c4);
      As[c4 + 0][r0] = av.x; As[c4 + 1][r0] = av.y;
      As[c4 + 2][r0] = av.z; As[c4 + 3][r0] = av.w;
      float4 av1 = *(const float4*)(arow1 + k0 + c4);
      As[c4 + 0][r1] = av1.x; As[c4 + 1][r1] = av1.y;
      As[c4 + 2][r1] = av1.z; As[c4 + 3][r1] = av1.w;
    }
#pragma unroll
    for (int i = 0; i < 2; i++) {
      int id = tid + 256 * i;
      int r = id >> 5;
      int c = (id & 31) << 2;
      *(float4*)&Bs[r][c] =
          *(const float4*)(W + (size_t)(k0 + r) * DD + n0 + c);
    }
    __syncthreads();
#pragma unroll
    for (int kk = 0; kk < 16; kk++) {
      float4 a0 = *(const float4*)&As[kk][tm * 8];
      float4 a1 = *(const float4*)&As[kk][tm * 8 + 4];
      float4 b0 = *(const float4*)&Bs[kk][tn * 8];
      float4 b1 = *(const float4*)&Bs[kk][tn * 8 + 4];
      float a[8] = {a0.x, a0.y, a0.z, a0.w, a1.x, a1.y, a1.z, a1.w};
      float b[8] = {b0.x, b0.y, b0.z, b0.w, b1.x, b1.y, b1.z, b1.w};
#pragma unroll
      for (int i = 0; i < 8; i++)
#pragma unroll
        for (int j = 0; j < 8; j++) acc[i][j] = fmaf(a[i], b[j], acc[i][j]);
    }
    __syncthreads();
  }
#pragma unroll
  for (int i = 0; i < 8; i++) {
    int m = m0 + tm * 8 + i;
    const float* brow = (mode == 2) ? (gpre + (size_t)(m / rowsPerTok) * DD)
                                    : biasVec;
#pragma unroll
    for (int j = 0; j < 8; j++) {
      int n = n0 + tn * 8 + j;
      float v = acc[i][j] + brow[n];
      if (mode >= 1) v = fmaxf(v, 0.f);
      acc[i][j] = v;
    }
    float* dst = C + (size_t)m * DD + n0 + tn * 8;
    float4 w0v, w1v;
    w0v.x = acc[i][0]; w0v.y = acc[i][1]; w0v.z = acc[i][2]; w0v.w = acc[i][3];
    w1v.x = acc[i][4]; w1v.y = acc[i][5]; w1v.z = acc[i][6]; w1v.w = acc[i][7];
    *(float4*)dst = w0v;
    *(float4*)(dst + 4) = w1v;
  }
}

// ---------------------------------------------------------------------------
// logits[row][a] = sum_n h1[row][n] * gna_w2[n][a] + b2[a]
// wave-per-row; gna_w2 staged transposed in LDS.
// ---------------------------------------------------------------------------
__global__ __launch_bounds__(256) void k_logits(
    const float* __restrict__ H1, const float* __restrict__ W2,
    const float* __restrict__ b2, float* __restrict__ L)
{
  __shared__ float sW2[NACT][DD];
  const int tid = threadIdx.x;
  for (int idx = tid; idx < NACT * DD; idx += 256) {
    int n = idx & (DD - 1);
    int a = idx >> 9;
    sW2[a][n] = W2[(size_t)n * NACT + a];
  }
  __syncthreads();
  const int wv = tid >> 6, lane = tid & 63;
  const int rbase = blockIdx.x * 16 + wv * 4;
  for (int rr = 0; rr < 4; rr++) {
    const int row = rbase + rr;
    const float* hrow = H1 + (size_t)row * DD;
    float accv[NACT];
#pragma unroll
    for (int a = 0; a < NACT; a++) accv[a] = 0.f;
#pragma unroll
    for (int i = 0; i < 8; i++) {
      float h = hrow[lane + 64 * i];
#pragma unroll
      for (int a = 0; a < NACT; a++) accv[a] += h * sW2[a][lane + 64 * i];
    }
#pragma unroll
    for (int a = 0; a < NACT; a++)
#pragma unroll
      for (int off = 32; off; off >>= 1) accv[a] += __shfl_xor(accv[a], off, 64);
    float outv = accv[0];
#pragma unroll
    for (int a = 1; a < NACT; a++)
      if (lane == a) outv = accv[a];
    if (lane < NACT) L[(size_t)row * NACT + lane] = outv + b2[lane];
  }
}

// ---------------------------------------------------------------------------
// Per-token: softmax -> combined -> stable top-k -> prob/act0 update ->
// (unless last turn) gather base, add action, layernorm, write new states.
// oldStates has per-token stride strideOld*DD (first beamNow rows valid).
// states written at FIXED stride NBEAM*DD -> per-token regions coincide
// across turns; no cross-token overlap (race-free).
// ---------------------------------------------------------------------------
__global__ __launch_bounds__(256) void k_update(
    const float* __restrict__ logits, const float* __restrict__ oldStates,
    float* __restrict__ states, float* __restrict__ prob,
    int* __restrict__ act0, const float* __restrict__ action,
    const float* __restrict__ lng, const float* __restrict__ lnb,
    int turn, int beamNow, int beamNext, int strideOld, int writeStates)
{
  __shared__ float sComb[NBEAM * NACT];
  __shared__ float sProbOld[NBEAM];
  __shared__ int   sAct0Old[NBEAM];
  __shared__ float sOld[NBEAM][DD];
  __shared__ int   sBeamIdx[NBEAM];
  __shared__ int   sActIdx[NBEAM];
  __shared__ int   sNewAct0[NBEAM];
  __shared__ float sNewProb[NBEAM];
  __shared__ float sRed[4];
  __shared__ float sMu, sInv;
  const int tid = threadIdx.x;
  const int token = blockIdx.x;

  if (tid < beamNow) {
    sProbOld[tid] = (turn == 0) ? 1.0f : prob[token * NBEAM + tid];
    sAct0Old[tid] = (turn == 0) ? 0 : act0[token * NBEAM + tid];
  }
  __syncthreads();
  if (tid < beamNow) {
    const float* lg = logits + ((size_t)token * beamNow + tid) * NACT;
    float l[NACT];
    float mx = -1e30f;
#pragma unroll
    for (int a = 0; a < NACT; a++) { l[a] = lg[a]; mx = fmaxf(mx, l[a]); }
    float e[NACT];
    float sum = 0.f;
#pragma unroll
    for (int a = 0; a < NACT; a++) { e[a] = expf(l[a] - mx); sum += e[a]; }
    float p = sProbOld[tid];
#pragma unroll
    for (int a = 0; a < NACT; a++) sComb[tid * NACT + a] = p * (e[a] / sum);
  }
  __syncthreads();
  if (tid < 64) {
    const int n = beamNow * NACT;
    float v0 = (tid < n) ? sComb[tid] : -1.f;
    float v1 = (tid + 64 < n) ? sComb[tid + 64] : -1.f;
    for (int it = 0; it < beamNext; it++) {
      unsigned long long key0 =
          ((unsigned long long)fmono(v0) << 32) | (unsigned)(0xFFFFFFFFu - tid);
      unsigned long long key1 =
          ((unsigned long long)fmono(v1) << 32) |
          (unsigned)(0xFFFFFFFFu - (tid + 64));
      unsigned long long best = key0 > key1 ? key0 : key1;
#pragma unroll
      for (int off = 1; off < 64; off <<= 1) {
        unsigned long long o = __shfl_xor(best, off, 64);
        if (o > best) best = o;
      }
      int jw = (int)(0xFFFFFFFFu - (unsigned)(best & 0xFFFFFFFFu));
      if (tid == 0) {
        int bi = jw >> 3, ai = jw & 7;
        sBeamIdx[it] = bi;
        sActIdx[it] = ai;
        sNewProb[it] = sComb[jw];
        sNewAct0[it] = (turn == 0) ? ai : sAct0Old[bi];
      }
      if (jw == tid) v0 = -1.f;
      if (jw == tid + 64) v1 = -1.f;
    }
  }
  __syncthreads();
  if (tid < beamNext) {
    prob[token * NBEAM + tid] = sNewProb[tid];
    act0[token * NBEAM + tid] = sNewAct0[tid];
  }
  if (!writeStates) return;

  const float* oldBase = oldStates + (size_t)token * strideOld * DD;
  for (int idx = tid; idx < beamNow * DD; idx += 256)
    (&sOld[0][0])[idx] = oldBase[idx];
  __syncthreads();
  const int lane = tid & 63, wv = tid >> 6;
  for (int jb = 0; jb < beamNext; jb++) {
    int bi = sBeamIdx[jb], ai = sActIdx[jb];
    float v0 = sOld[bi][tid] + action[(size_t)ai * DD + tid];
    float v1 = sOld[bi][tid + 256] + action[(size_t)ai * DD + tid + 256];
    float s = v0 + v1;
#pragma unroll
    for (int off = 32; off; off >>= 1) s += __shfl_xor(s, off, 64);
    if (lane == 0) sRed[wv] = s;
    __syncthreads();
    if (tid == 0) sMu = (sRed[0] + sRed[1] + sRed[2] + sRed[3]) * (1.f / DD);
    __syncthreads();
    float mu = sMu;
    float h0 = v0 - mu, h1v = v1 - mu;
    float q = h0 * h0 + h1v * h1v;
#pragma unroll
    for (int off = 32; off; off >>= 1) q += __shfl_xor(q, off, 64);
    if (lane == 0) sRed[wv] = q;
    __syncthreads();
    if (tid == 0)
      sInv = 1.0f /
             sqrtf((sRed[0] + sRed[1] + sRed[2] + sRed[3]) * (1.f / DD) + LNEPS);
    __syncthreads();
    float inv = sInv;
    float* dst = states + ((size_t)token * NBEAM + jb) * DD;
    dst[tid] = h0 * inv * lng[tid] + lnb[tid];
    dst[tid + 256] = h1v * inv * lng[tid + 256] + lnb[tid + 256];
    __syncthreads();
  }
}

// ---------------------------------------------------------------------------
// Final: best beam (argmax, first max), its first action, LN stats of
// states0 + action[a].
// ---------------------------------------------------------------------------
__global__ __launch_bounds__(256) void k_final_prep(
    const float* __restrict__ prob, const int* __restrict__ act0,
    const float* __restrict__ states0, const float* __restrict__ action,
    int* __restrict__ abest, float* __restrict__ muA, float* __restrict__ invA)
{
  __shared__ int sA;
  __shared__ float sRed[4];
  __shared__ float sMu;
  const int tid = threadIdx.x;
  const int token = blockIdx.x;
  if (tid == 0) {
    float best = prob[token * NBEAM];
    int bi = 0;
    for (int j = 1; j < NBEAM; j++) {
      float v = prob[token * NBEAM + j];
      if (v > best) { best = v; bi = j; }
    }
    sA = act0[token * NBEAM + bi];
  }
  __syncthreads();
  const int a = sA;
  const int lane = tid & 63, wv = tid >> 6;
  float v0 = states0[(size_t)token * DD + tid] + action[(size_t)a * DD + tid];
  float v1 = states0[(size_t)token * DD + tid + 256] +
             action[(size_t)a * DD + tid + 256];
  float s = v0 + v1;
#pragma unroll
  for (int off = 32; off; off >>= 1) s += __shfl_xor(s, off, 64);
  if (lane == 0) sRed[wv] = s;
  __syncthreads();
  if (tid == 0) sMu = (sRed[0] + sRed[1] + sRed[2] + sRed[3]) * (1.f / DD);
  __syncthreads();
  float mu = sMu;
  float h0 = v0 - mu, h1v = v1 - mu;
  float q = h0 * h0 + h1v * h1v;
#pragma unroll
  for (int off = 32; off; off >>= 1) q += __shfl_xor(q, off, 64);
  if (lane == 0) sRed[wv] = q;
  __syncthreads();
  if (tid == 0) {
    float var = (sRed[0] + sRed[1] + sRed[2] + sRed[3]) * (1.f / DD);
    muA[token] = mu;
    invA[token] = 1.0f / sqrtf(var + LNEPS);
    abest[token] = a;
  }
}

// ---------------------------------------------------------------------------
// Final transposed write: out[b, d, s] via 32x64 LDS tile.
// ---------------------------------------------------------------------------
__global__ __launch_bounds__(256) void k_final_write(
    const float* __restrict__ states0, const float* __restrict__ action,
    const int* __restrict__ abest, const float* __restrict__ muA,
    const float* __restrict__ invA, const float* __restrict__ lng,
    const float* __restrict__ lnb, float* __restrict__ out)
{
  __shared__ float tile[32][65];
  const int t0 = blockIdx.x * 32;
  const int d0 = blockIdx.y * 64;
  const int tid = threadIdx.x;
  {
    int r = tid >> 3;
    int c = (tid & 7) * 8;
    int token = t0 + r;
    int a = abest[token];
    float mu = muA[token], inv = invA[token];
#pragma unroll
    for (int q = 0; q < 8; q++) {
      int d = d0 + c + q;
      float v = (states0[(size_t)token * DD + d] + action[(size_t)a * DD + d] -
                 mu) * inv * lng[d] + lnb[d];
      tile[r][c + q] = v;
    }
  }
  __syncthreads();
  {
    int dl = tid >> 2;
    int sc = (tid & 3) * 8;
    int b = t0 >> 11;
    int s0 = (t0 & 2047);
    float* dst = out + ((size_t)(b * DD + d0 + dl)) * SS + s0 + sc;
    float4 w0v, w1v;
    w0v.x = tile[sc + 0][dl]; w0v.y = tile[sc + 1][dl];
    w0v.z = tile[sc + 2][dl]; w0v.w = tile[sc + 3][dl];
    w1v.x = tile[sc + 4][dl]; w1v.y = tile[sc + 5][dl];
    w1v.z = tile[sc + 6][dl]; w1v.w = tile[sc + 7][dl];
    *(float4*)dst = w0v;
    *(float4*)(dst + 4) = w1v;
  }
}

// ---------------------------------------------------------------------------
extern "C" void kernel_launch(void* const* d_in, const int* in_sizes, int n_in,
                              void* d_out, int out_size, void* d_ws,
                              size_t ws_size, hipStream_t stream) {
  const float* x      = (const float*)d_in[0];
  const float* weight = (const float*)d_in[1];
  const float* c2s_w1 = (const float*)d_in[2];
  const float* c2s_b1 = (const float*)d_in[3];
  const float* c2s_w2 = (const float*)d_in[4];
  const float* c2s_b2 = (const float*)d_in[5];
  const float* eg_w1  = (const float*)d_in[6];
  const float* eg_b1  = (const float*)d_in[7];
  const float* eg_w2  = (const float*)d_in[8];
  const float* eg_b2  = (const float*)d_in[9];
  const float* gna_w1 = (const float*)d_in[10];
  const float* gna_b1 = (const float*)d_in[11];
  const float* gna_w2 = (const float*)d_in[12];
  const float* gna_b2 = (const float*)d_in[13];
  const float* action = (const float*)d_in[14];
  const float* ln_g   = (const float*)d_in[15];
  const float* ln_b   = (const float*)d_in[16];
  float* out = (float*)d_out;

  float* ws = (float*)d_ws;
  size_t o = 0;
  float* ct      = ws + o; o += (size_t)TOK * DD;
  float* htmp    = ws + o; o += (size_t)TOK * DD;
  float* states0 = ws + o; o += (size_t)TOK * DD;
  float* goal    = ws + o; o += (size_t)TOK * DD;
  float* gpre    = ws + o; o += (size_t)TOK * DD;
  float* states  = ws + o; o += (size_t)TOK * NBEAM * DD;   // [token][10][D]
  float* h1      = ws + o; o += (size_t)TOK * NBEAM * DD;
  float* logitsB = ws + o; o += (size_t)TOK * NBEAM * NACT;
  float* probB   = ws + o; o += (size_t)TOK * NBEAM;
  int*   act0B   = (int*)(ws + o); o += (size_t)TOK * NBEAM;
  int*   abest   = (int*)(ws + o); o += TOK;
  float* muA     = ws + o; o += TOK;
  float* invA    = ws + o; o += TOK;

  dim3 blk(256);
  // Phase A: causal mix + c2s/eg MLPs + goal's gna contribution (once).
  k_gemm_tril<<<dim3(16, 16), blk, 0, stream>>>(x, weight, ct);
  k_gemm512<<<dim3(TOK / 128, 4), blk, 0, stream>>>(ct, c2s_w1, c2s_b1, gpre, 1, 1, htmp, 1);
  k_gemm512<<<dim3(TOK / 128, 4), blk, 0, stream>>>(htmp, c2s_w2, c2s_b2, gpre, 1, 1, states0, 0);
  k_gemm512<<<dim3(TOK / 128, 4), blk, 0, stream>>>(ct, eg_w1, eg_b1, gpre, 1, 1, htmp, 1);
  k_gemm512<<<dim3(TOK / 128, 4), blk, 0, stream>>>(htmp, eg_w2, eg_b2, gpre, 1, 1, goal, 0);
  k_gemm512<<<dim3(TOK / 128, 4), blk, 0, stream>>>(goal, gna_w1 + (size_t)DD * DD, gna_b1, gpre, 1, 1, gpre, 0);

  // Phase B: 7 beam turns. states buffer uses fixed [token][10][D] layout.
  for (int turn = 0; turn < 7; turn++) {
    int beamNow  = (turn == 0) ? 1 : ((turn == 1) ? 8 : 10);
    int beamNext = (turn == 0) ? 8 : 10;
    int rows = TOK * beamNow;
    const float* cur = (turn == 0) ? states0 : states;
    int strideOld    = (turn == 0) ? 1 : NBEAM;
    k_gemm512<<<dim3(rows / 128, 4), blk, 0, stream>>>(
        cur, gna_w1, gna_b1, gpre, beamNow, strideOld, h1, 2);
    k_logits<<<dim3(rows / 16), blk, 0, stream>>>(h1, gna_w2, gna_b2, logitsB);
    k_update<<<dim3(TOK), blk, 0, stream>>>(logitsB, cur, states, probB, act0B,
                                            action, ln_g, ln_b, turn, beamNow,
                                            beamNext, strideOld,
                                            (turn < 6) ? 1 : 0);
  }

  // Phase C: final selection + layernorm + transposed write.
  k_final_prep<<<dim3(TOK), blk, 0, stream>>>(probB, act0B, states0, action, abest, muA, invA);
  k_final_write<<<dim3(TOK / 32, DD / 64), blk, 0, stream>>>(states0, action, abest, muA, invA, ln_g, ln_b, out);

  (void)in_sizes; (void)n_in; (void)out_size; (void)ws_size;
}